// Round 9
// baseline (229.945 us; speedup 1.0000x reference)
//
#include <hip/hip_runtime.h>
#include <stdint.h>

#define B_  4
#define H_  16
#define N_  1024
#define D_  64
#define SS_R 328   // halfs per i-row of Ss: [i in 0..32)][j*20 + h], +8 pad

typedef _Float16 half4v __attribute__((ext_vector_type(4)));
typedef _Float16 half8v __attribute__((ext_vector_type(8)));
typedef float    f32x4  __attribute__((ext_vector_type(4)));

// workspace layout (bytes)
#define VT_OFF   0
#define VT_SZ    (B_ * H_ * D_ * N_ * 2)             // 8 MB
#define LB_OFF   (VT_OFF + VT_SZ)
#define LB_SZ    (B_ * H_ * N_ * 4)                  // 256 KB
#define E_OFF    (LB_OFF + LB_SZ)
#define E_SZ     ((size_t)B_ * 2080 * 4096 * 2)      // 65 MB causal-packed E/A2
#define LV_OFF   (E_OFF + E_SZ)
#define LV_SZ    (B_ * N_ * H_ * 4)                  // 256 KB
#define WS_NEED  ((size_t)LV_OFF + LV_SZ)            // 73.5 MB (< proven 80.25)

__device__ __forceinline__ half4v cvt4(f32x4 v) {
    half4v h;
    h[0] = (_Float16)v[0]; h[1] = (_Float16)v[1];
    h[2] = (_Float16)v[2]; h[3] = (_Float16)v[3];
    return h;
}

// decode blockIdx (0..511) -> slot grouped per XCD (consecutive slots same XCD)
__device__ __forceinline__ int xcd_slot(int x) { return (x >> 3) + (x & 7) * 64; }

// ---------------- prep: V transpose to f16 VT[b,h,d,j] ----------------
__global__ __launch_bounds__(256)
void prep_vt(const float* __restrict__ v, _Float16* __restrict__ VT) {
    __shared__ float T[64 * 67];
    const int t = threadIdx.x;
    const int bh = blockIdx.x >> 4, jb = blockIdx.x & 15, j0 = jb * 64;
    const float* src = v + ((size_t)bh * N_ + j0) * D_;
    #pragma unroll
    for (int m = 0; m < 4; ++m) {
        const int flat = m * 1024 + t * 4;
        const int j = flat >> 6, d0 = flat & 63;
        f32x4 val = *(const f32x4*)(src + flat);
        #pragma unroll
        for (int e = 0; e < 4; ++e) T[j * 67 + d0 + e] = val[e];
    }
    __syncthreads();
    const int d = t >> 2, jq = t & 3;
    half8v a, b2;
    #pragma unroll
    for (int jj = 0; jj < 8; ++jj) a[jj]  = (_Float16)T[(16 * jq + jj) * 67 + d];
    #pragma unroll
    for (int jj = 0; jj < 8; ++jj) b2[jj] = (_Float16)T[(16 * jq + 8 + jj) * 67 + d];
    _Float16* dst = VT + ((size_t)bh * D_ + d) * N_ + j0 + jq * 16;
    *(half8v*)dst = a;
    *(half8v*)(dst + 8) = b2;
}

// ---------------- sweep 1: l (atomic) + E cache (f16, causal-packed) ----------------
__global__ __launch_bounds__(512, 2)
void attend_sweep1(const float* __restrict__ q, const float* __restrict__ k,
                   const float* __restrict__ Wpre, float* __restrict__ lbuf,
                   _Float16* __restrict__ Ebuf) {
    __shared__ _Float16 Ss[2][32 * SS_R];   // 41,984 B

    const int slot = xcd_slot(blockIdx.x);
    const int b = slot >> 7;
    const int r7 = slot & 127;
    const int m = r7 >> 2, phase = r7 & 3;
    const int itA = m, itB = 63 - m;
    const int i0A = m * 16, i0B = itB * 16;
    const int triA = itA * (itA + 1) / 2, triB = itB * (itB + 1) / 2;

    const int t = threadIdx.x;
    const int lane = t & 63, w = t >> 6;        // 8 waves
    const int l16 = lane & 15, lg = lane >> 4;
    const int h0 = 2 * w;
    const size_t bh0 = (size_t)b * H_;
    _Float16* Eb = Ebuf + (size_t)b * 2080 * 4096;

    const half4v wpre_f = cvt4(*(const f32x4*)(Wpre + l16 * 16 + 4 * lg));

    half4v qf[2][2][4];
    #pragma unroll
    for (int s = 0; s < 2; ++s) {
        const int i0s = s ? i0B : i0A;
        #pragma unroll
        for (int e = 0; e < 2; ++e) {
            const float* qrow = q + ((bh0 + h0 + e) * N_ + i0s + l16) * D_;
            #pragma unroll
            for (int kk = 0; kk < 4; ++kk) {
                f32x4 qv = *(const f32x4*)(qrow + kk * 16 + 4 * lg);
                half4v hv;
                #pragma unroll
                for (int x = 0; x < 4; ++x) hv[x] = (_Float16)(qv[x] * 0.125f);
                qf[s][e][kk] = hv;
            }
        }
    }

    float lp[4][4];
    #pragma unroll
    for (int ss = 0; ss < 4; ++ss)
        #pragma unroll
        for (int r = 0; r < 4; ++r) lp[ss][r] = 0.f;

    int pbuf = 0;
    for (int sb = phase; 2 * sb <= itB; sb += 4) {
        #pragma unroll
        for (int u = 0; u < 2; ++u) {
            const int jt = 2 * sb + u;
            if (jt > itB) break;
            const int j0 = jt * 16;
            const bool actA = (jt <= itA);
            half4v kf[2][4];
            #pragma unroll
            for (int e = 0; e < 2; ++e) {
                const float* krow = k + ((bh0 + h0 + e) * N_ + j0 + l16) * D_ + 4 * lg;
                #pragma unroll
                for (int kk = 0; kk < 4; ++kk) kf[e][kk] = cvt4(*(const f32x4*)(krow + kk * 16));
            }
            #pragma unroll
            for (int s = 0; s < 2; ++s) {
                if (s == 0 && !actA) continue;
                #pragma unroll
                for (int e = 0; e < 2; ++e) {
                    f32x4 acc = {0.f, 0.f, 0.f, 0.f};
                    #pragma unroll
                    for (int kk = 0; kk < 4; ++kk)
                        acc = __builtin_amdgcn_mfma_f32_16x16x16f16(qf[s][e][kk], kf[e][kk], acc, 0, 0, 0);
                    #pragma unroll
                    for (int r = 0; r < 4; ++r)
                        Ss[pbuf][(s * 16 + 4 * lg + r) * SS_R + l16 * 20 + h0 + e] = (_Float16)acc[r];
                }
            }
            __syncthreads();
            #pragma unroll
            for (int ss = 0; ss < 4; ++ss) {
                const int strip = ss >> 1;
                if (strip == 0 && !actA) continue;
                const int sii = (ss & 1) * 8 + w;
                const int its = strip ? itB : itA;
                const int tri = strip ? triB : triA;
                half4v sfrag = *(const half4v*)&Ss[pbuf][(strip * 16 + sii) * SS_R + l16 * 20 + 4 * lg];
                f32x4 z = {0.f, 0.f, 0.f, 0.f};
                f32x4 m1 = __builtin_amdgcn_mfma_f32_16x16x16f16(wpre_f, sfrag, z, 0, 0, 0);
                const bool ok = (jt < its) || (l16 <= sii);
                half4v ev;
                #pragma unroll
                for (int r = 0; r < 4; ++r) {
                    const float e_ = ok ? __expf(m1[r]) : 0.f;
                    lp[ss][r] += e_;
                    ev[r] = (_Float16)e_;
                }
                *(half4v*)(Eb + (size_t)(tri + jt) * 4096 + (sii * 16 + l16) * 16 + 4 * lg) = ev;
            }
            pbuf ^= 1;
        }
    }

    #pragma unroll
    for (int ss = 0; ss < 4; ++ss) {
        const int strip = ss >> 1;
        const int sii = (ss & 1) * 8 + w;
        const int i0s = strip ? i0B : i0A;
        #pragma unroll
        for (int r = 0; r < 4; ++r) {
            float val = lp[ss][r];
            val += __shfl_xor(val, 1, 64);
            val += __shfl_xor(val, 2, 64);
            val += __shfl_xor(val, 4, 64);
            val += __shfl_xor(val, 8, 64);
            if (l16 == 0)
                atomicAdd(&lbuf[(bh0 + 4 * lg + r) * N_ + i0s + sii], val);
        }
    }
}

// ---------------- linv: [b][i][h] = 1/lbuf[b][h][i] ----------------
__global__ __launch_bounds__(256)
void linv_prep(const float* __restrict__ lbuf, float* __restrict__ linv) {
    const int x = blockIdx.x * 256 + threadIdx.x;    // 65536
    const int b = x >> 14, h = (x >> 10) & 15, i = x & 1023;
    linv[(((size_t)b << 10) + i) * 16 + h] = 1.0f / lbuf[x];
}

// ---------------- mix2: in-place E -> A2 (barrier-free, one wave per tile) ----------------
// reads  tile[pixel(i,j)][h]  (E, h contig)
// writes tile[g][i][j]        (A2, j contig)
__global__ __launch_bounds__(512, 2)
void mix2_pass(_Float16* __restrict__ Ebuf, const float* __restrict__ linv,
               const float* __restrict__ Wpost) {
    const int t = threadIdx.x;
    const int lane = t & 63, w = t >> 6;
    const int l16 = lane & 15, lg = lane >> 4;
    const int wid = blockIdx.x * 8 + w;          // 0..4095

    const half4v wpost_f = cvt4(*(const f32x4*)(Wpost + l16 * 16 + 4 * lg));

    for (int gT = wid; gT < B_ * 2080; gT += 4096) {
        const int b = gT / 2080;
        const int T = gT - b * 2080;
        int it = (int)((sqrtf(8.0f * (float)T + 1.0f) - 1.0f) * 0.5f);
        while ((it + 1) * (it + 2) / 2 <= T) ++it;
        while (it * (it + 1) / 2 > T) --it;
        const int i0 = it * 16;
        _Float16* tile = Ebuf + (size_t)gT * 4096;
        const float* lv = linv + (((size_t)b << 10) + i0) * 16 + 4 * lg;

        // read full tile (A-frags: m=j on lanes, k=h on regs) BEFORE any write
        half4v ef[16];
        #pragma unroll
        for (int i = 0; i < 16; ++i)
            ef[i] = *(const half4v*)(tile + (i * 16 + l16) * 16 + 4 * lg);
        __builtin_amdgcn_sched_barrier(0);
        // per i-row: scale by 1/l[h,i], mix with Wpost, store j-contiguous
        #pragma unroll
        for (int i = 0; i < 16; ++i) {
            f32x4 lvv = *(const f32x4*)(lv + i * 16);
            half4v af;
            #pragma unroll
            for (int e = 0; e < 4; ++e)
                af[e] = (_Float16)((float)ef[i][e] * lvv[e]);
            f32x4 z = {0.f, 0.f, 0.f, 0.f};
            f32x4 m2 = __builtin_amdgcn_mfma_f32_16x16x16f16(af, wpost_f, z, 0, 0, 0);
            *(half4v*)(tile + l16 * 256 + i * 16 + 4 * lg) = cvt4(m2);
        }
    }
}

// ---------------- pv: out[g,i,d] = sum_j A2[g,i,j] * VT[d,j] (barrier-free) ----------------
__global__ __launch_bounds__(512, 2)
void pv_pass(const _Float16* __restrict__ Ebuf, const _Float16* __restrict__ VT,
             float* __restrict__ out) {
    const int t = threadIdx.x;
    const int lane = t & 63, w = t >> 6;
    const int l16 = lane & 15, lg = lane >> 4;
    const int r = blockIdx.x >> 3;                 // 0..63, mirror-interleaved it
    const int it = (r & 1) ? (r >> 1) : 63 - (r >> 1);
    const int sub = blockIdx.x & 7;
    const int b = sub >> 1, oct = sub & 1;
    const int g = oct * 8 + w;
    const size_t tri = (size_t)it * (it + 1) / 2;

    const _Float16* A2 = Ebuf + ((size_t)b * 2080 + tri) * 4096 + g * 256 + l16 * 16 + 4 * lg;
    const _Float16* vb = VT + (((size_t)b * H_ + g) * D_) * N_;

    f32x4 oacc[4];
    #pragma unroll
    for (int ds = 0; ds < 4; ++ds) oacc[ds] = (f32x4){0.f, 0.f, 0.f, 0.f};

    #pragma unroll 4
    for (int jt = 0; jt <= it; ++jt) {
        half4v bf = *(const half4v*)(A2 + (size_t)jt * 4096);
        half4v vf[4];
        #pragma unroll
        for (int ds = 0; ds < 4; ++ds)
            vf[ds] = *(const half4v*)(vb + (size_t)(ds * 16 + l16) * N_ + jt * 16 + 4 * lg);
        #pragma unroll
        for (int ds = 0; ds < 4; ++ds)
            oacc[ds] = __builtin_amdgcn_mfma_f32_16x16x16f16(vf[ds], bf, oacc[ds], 0, 0, 0);
    }

    float* orow = out + (((size_t)b * H_ + g) * N_ + it * 16 + l16) * D_;
    #pragma unroll
    for (int ds = 0; ds < 4; ++ds)
        *(f32x4*)&orow[ds * 16 + 4 * lg] = oacc[ds];
}

// ---------------- fallback: fused mirror-pair kernel (ws-free, verified R6) ----------------
__global__ __launch_bounds__(512, 2)
void attend_fused(const float* __restrict__ q, const float* __restrict__ k,
                  const float* __restrict__ v, const float* __restrict__ Wpre,
                  const float* __restrict__ Wpost, float* __restrict__ out) {
    __shared__ _Float16 Ss[32 * SS_R];
    __shared__ _Float16 A2s[16 * 648];

    const int t = threadIdx.x;
    const int b = blockIdx.x >> 5;
    const int m = blockIdx.x & 31;
    const int itA = m, itB = 63 - m;
    const int i0A = m * 16, i0B = (63 - m) * 16;

    const int lane = t & 63, w = t >> 6;
    const int l16 = lane & 15, lg = lane >> 4;
    const int h0 = 2 * w;
    const size_t bh0 = (size_t)b * H_;

    const half4v wpre_f  = cvt4(*(const f32x4*)(Wpre  + l16 * 16 + 4 * lg));
    const half4v wpost_f = cvt4(*(const f32x4*)(Wpost + l16 * 16 + 4 * lg));

    half4v qf[2][2][4];
    #pragma unroll
    for (int s = 0; s < 2; ++s) {
        const int i0s = s ? i0B : i0A;
        #pragma unroll
        for (int e = 0; e < 2; ++e) {
            const float* qrow = q + ((bh0 + h0 + e) * N_ + i0s + l16) * D_;
            #pragma unroll
            for (int kk = 0; kk < 4; ++kk) {
                f32x4 qv = *(const f32x4*)(qrow + kk * 16 + 4 * lg);
                half4v hv;
                #pragma unroll
                for (int x = 0; x < 4; ++x) hv[x] = (_Float16)(qv[x] * 0.125f);
                qf[s][e][kk] = hv;
            }
        }
    }

    float lp[4][4];
    #pragma unroll
    for (int ss = 0; ss < 4; ++ss)
        #pragma unroll
        for (int r = 0; r < 4; ++r) lp[ss][r] = 0.f;

    for (int jt = 0; jt <= itB; ++jt) {
        const int j0 = jt * 16;
        const bool actA = (jt <= itA);
        half4v kf[2][4];
        #pragma unroll
        for (int e = 0; e < 2; ++e) {
            const float* krow = k + ((bh0 + h0 + e) * N_ + j0 + l16) * D_ + 4 * lg;
            #pragma unroll
            for (int kk = 0; kk < 4; ++kk) kf[e][kk] = cvt4(*(const f32x4*)(krow + kk * 16));
        }
        #pragma unroll
        for (int s = 0; s < 2; ++s) {
            if (s == 0 && !actA) continue;
            #pragma unroll
            for (int e = 0; e < 2; ++e) {
                f32x4 acc = {0.f, 0.f, 0.f, 0.f};
                #pragma unroll
                for (int kk = 0; kk < 4; ++kk)
                    acc = __builtin_amdgcn_mfma_f32_16x16x16f16(qf[s][e][kk], kf[e][kk], acc, 0, 0, 0);
                #pragma unroll
                for (int r = 0; r < 4; ++r)
                    Ss[(s * 16 + 4 * lg + r) * SS_R + l16 * 20 + h0 + e] = (_Float16)acc[r];
            }
        }
        __syncthreads();
        #pragma unroll
        for (int ss = 0; ss < 4; ++ss) {
            const int strip = ss >> 1;
            if (strip == 0 && !actA) continue;
            const int sii = (ss & 1) * 8 + w;
            const int its = strip ? itB : itA;
            half4v sfrag = *(const half4v*)&Ss[(strip * 16 + sii) * SS_R + l16 * 20 + 4 * lg];
            f32x4 z = {0.f, 0.f, 0.f, 0.f};
            f32x4 m1 = __builtin_amdgcn_mfma_f32_16x16x16f16(wpre_f, sfrag, z, 0, 0, 0);
            if ((jt < its) || (l16 <= sii)) {
                #pragma unroll
                for (int r = 0; r < 4; ++r) lp[ss][r] += __expf(m1[r]);
            }
        }
        __syncthreads();
    }

    float lrec[4][4];
    #pragma unroll
    for (int ss = 0; ss < 4; ++ss)
        #pragma unroll
        for (int r = 0; r < 4; ++r) {
            float val = lp[ss][r];
            val += __shfl_xor(val, 1, 64);
            val += __shfl_xor(val, 2, 64);
            val += __shfl_xor(val, 4, 64);
            val += __shfl_xor(val, 8, 64);
            lrec[ss][r] = 1.0f / val;
        }

    f32x4 oacc[2][2][4];
    #pragma unroll
    for (int s = 0; s < 2; ++s)
        #pragma unroll
        for (int e = 0; e < 2; ++e)
            #pragma unroll
            for (int ds = 0; ds < 4; ++ds)
                oacc[s][e][ds] = (f32x4){0.f, 0.f, 0.f, 0.f};

    for (int jt = 0; jt <= itB; ++jt) {
        const int j0 = jt * 16;
        const bool actA = (jt <= itA);
        half4v kf[2][4];
        #pragma unroll
        for (int e = 0; e < 2; ++e) {
            const float* krow = k + ((bh0 + h0 + e) * N_ + j0 + l16) * D_ + 4 * lg;
            #pragma unroll
            for (int kk = 0; kk < 4; ++kk) kf[e][kk] = cvt4(*(const f32x4*)(krow + kk * 16));
        }
        half4v vf[2][4];
        #pragma unroll
        for (int e = 0; e < 2; ++e)
            #pragma unroll
            for (int ds = 0; ds < 4; ++ds) {
                f32x4 vv;
                #pragma unroll
                for (int xx = 0; xx < 4; ++xx)
                    vv[xx] = v[((bh0 + h0 + e) * N_ + j0 + 4 * lg + xx) * D_ + ds * 16 + l16];
                vf[e][ds] = cvt4(vv);
            }
        #pragma unroll
        for (int s = 0; s < 2; ++s) {
            if (s == 0 && !actA) continue;
            #pragma unroll
            for (int e = 0; e < 2; ++e) {
                f32x4 acc = {0.f, 0.f, 0.f, 0.f};
                #pragma unroll
                for (int kk = 0; kk < 4; ++kk)
                    acc = __builtin_amdgcn_mfma_f32_16x16x16f16(qf[s][e][kk], kf[e][kk], acc, 0, 0, 0);
                #pragma unroll
                for (int r = 0; r < 4; ++r)
                    Ss[(s * 16 + 4 * lg + r) * SS_R + l16 * 20 + h0 + e] = (_Float16)acc[r];
            }
        }
        __syncthreads();
        #pragma unroll
        for (int ss = 0; ss < 4; ++ss) {
            const int strip = ss >> 1;
            if (strip == 0 && !actA) continue;
            const int sii = (ss & 1) * 8 + w;
            const int its = strip ? itB : itA;
            half4v sfrag = *(const half4v*)&Ss[(strip * 16 + sii) * SS_R + l16 * 20 + 4 * lg];
            f32x4 z = {0.f, 0.f, 0.f, 0.f};
            f32x4 m1 = __builtin_amdgcn_mfma_f32_16x16x16f16(wpre_f, sfrag, z, 0, 0, 0);
            const bool ok = (jt < its) || (l16 <= sii);
            half4v pfrag;
            #pragma unroll
            for (int r = 0; r < 4; ++r)
                pfrag[r] = (_Float16)(ok ? __expf(m1[r]) * lrec[ss][r] : 0.f);
            f32x4 m2 = __builtin_amdgcn_mfma_f32_16x16x16f16(wpost_f, pfrag, z, 0, 0, 0);
            #pragma unroll
            for (int r = 0; r < 4; ++r)
                A2s[(4 * lg + r) * 648 + (strip * 16 + sii) * 20 + l16] = (_Float16)m2[r];
        }
        __syncthreads();
        #pragma unroll
        for (int s = 0; s < 2; ++s) {
            if (s == 0 && !actA) continue;
            #pragma unroll
            for (int e = 0; e < 2; ++e) {
                half4v bfrag = *(const half4v*)&A2s[(h0 + e) * 648 + (s * 16 + l16) * 20 + 4 * lg];
                #pragma unroll
                for (int ds = 0; ds < 4; ++ds)
                    oacc[s][e][ds] = __builtin_amdgcn_mfma_f32_16x16x16f16(vf[e][ds], bfrag, oacc[s][e][ds], 0, 0, 0);
            }
        }
    }

    #pragma unroll
    for (int s = 0; s < 2; ++s) {
        const int i0s = s ? i0B : i0A;
        #pragma unroll
        for (int e = 0; e < 2; ++e) {
            float* orow = out + ((bh0 + h0 + e) * N_ + i0s + l16) * D_;
            #pragma unroll
            for (int ds = 0; ds < 4; ++ds)
                *(f32x4*)&orow[ds * 16 + 4 * lg] = oacc[s][e][ds];
        }
    }
}

extern "C" void kernel_launch(void* const* d_in, const int* in_sizes, int n_in,
                              void* d_out, int out_size, void* d_ws, size_t ws_size,
                              hipStream_t stream) {
    const float* q     = (const float*)d_in[0];
    const float* k     = (const float*)d_in[1];
    const float* v     = (const float*)d_in[2];
    const float* Wpre  = (const float*)d_in[3];
    const float* Wpost = (const float*)d_in[4];
    float* out = (float*)d_out;
    _Float16* VT   = (_Float16*)((char*)d_ws + VT_OFF);
    float*    lbuf = (float*)((char*)d_ws + LB_OFF);
    _Float16* Ebuf = (_Float16*)((char*)d_ws + E_OFF);
    float*    linv = (float*)((char*)d_ws + LV_OFF);

    if (ws_size >= WS_NEED) {
        prep_vt<<<dim3(B_ * H_ * (N_ / 64)), dim3(256), 0, stream>>>(v, VT);
        hipMemsetAsync((char*)d_ws + LB_OFF, 0, LB_SZ, stream);
        attend_sweep1<<<dim3(512), dim3(512), 0, stream>>>(q, k, Wpre, lbuf, Ebuf);
        linv_prep<<<dim3(256), dim3(256), 0, stream>>>(lbuf, linv);
        mix2_pass<<<dim3(512), dim3(512), 0, stream>>>(Ebuf, linv, Wpost);
        pv_pass<<<dim3(512), dim3(512), 0, stream>>>(Ebuf, VT, out);
    } else {
        attend_fused<<<dim3(B_ * 32), dim3(512), 0, stream>>>(q, k, v, Wpre, Wpost, out);
    }
}

// Round 10
// 209.807 us; speedup vs baseline: 1.0960x; 1.0960x over previous
//
#include <hip/hip_runtime.h>
#include <stdint.h>

#define B_  4
#define H_  16
#define N_  1024
#define D_  64
#define SS_R 328   // halfs per i-row of Ss: [i in 0..32)][j*20 + h], +8 pad
#define A2_R 328   // halfs per g-row of A2s: [g][i*20 + j], +8 pad

typedef _Float16 half4v __attribute__((ext_vector_type(4)));
typedef _Float16 half8v __attribute__((ext_vector_type(8)));
typedef float    f32x4  __attribute__((ext_vector_type(4)));

// workspace layout (bytes)
#define VT_OFF   0
#define VT_SZ    (B_ * H_ * D_ * N_ * 2)             // 8 MB
#define LB_OFF   (VT_OFF + VT_SZ)
#define LB_SZ    (B_ * H_ * N_ * 4)                  // 256 KB
#define E_OFF    (LB_OFF + LB_SZ)
#define E_SZ     ((size_t)B_ * 2080 * 4096 * 2)      // 65 MB causal-packed E
#define WS_NEED  ((size_t)E_OFF + E_SZ)              // 73.25 MB (< proven 80.25)

__device__ __forceinline__ half4v cvt4(f32x4 v) {
    half4v h;
    h[0] = (_Float16)v[0]; h[1] = (_Float16)v[1];
    h[2] = (_Float16)v[2]; h[3] = (_Float16)v[3];
    return h;
}

// decode blockIdx (0..511) -> slot grouped per XCD (consecutive slots same XCD)
__device__ __forceinline__ int xcd_slot(int x) { return (x >> 3) + (x & 7) * 64; }

// ---------------- prep: V transpose to f16 VT[b,h,d,j] ----------------
__global__ __launch_bounds__(256)
void prep_vt(const float* __restrict__ v, _Float16* __restrict__ VT) {
    __shared__ float T[64 * 67];
    const int t = threadIdx.x;
    const int bh = blockIdx.x >> 4, jb = blockIdx.x & 15, j0 = jb * 64;
    const float* src = v + ((size_t)bh * N_ + j0) * D_;
    #pragma unroll
    for (int m = 0; m < 4; ++m) {
        const int flat = m * 1024 + t * 4;
        const int j = flat >> 6, d0 = flat & 63;
        f32x4 val = *(const f32x4*)(src + flat);
        #pragma unroll
        for (int e = 0; e < 4; ++e) T[j * 67 + d0 + e] = val[e];
    }
    __syncthreads();
    const int d = t >> 2, jq = t & 3;
    half8v a, b2;
    #pragma unroll
    for (int jj = 0; jj < 8; ++jj) a[jj]  = (_Float16)T[(16 * jq + jj) * 67 + d];
    #pragma unroll
    for (int jj = 0; jj < 8; ++jj) b2[jj] = (_Float16)T[(16 * jq + 8 + jj) * 67 + d];
    _Float16* dst = VT + ((size_t)bh * D_ + d) * N_ + j0 + jq * 16;
    *(half8v*)dst = a;
    *(half8v*)(dst + 8) = b2;
}

// ---------------- sweep 1: l (atomic) + E cache (f16, causal-packed) ----------------
__global__ __launch_bounds__(512, 2)
void attend_sweep1(const float* __restrict__ q, const float* __restrict__ k,
                   const float* __restrict__ Wpre, float* __restrict__ lbuf,
                   _Float16* __restrict__ Ebuf) {
    __shared__ _Float16 Ss[2][32 * SS_R];   // 41,984 B

    const int slot = xcd_slot(blockIdx.x);
    const int b = slot >> 7;
    const int r7 = slot & 127;
    const int m = r7 >> 2, phase = r7 & 3;
    const int itA = m, itB = 63 - m;
    const int i0A = m * 16, i0B = itB * 16;
    const int triA = itA * (itA + 1) / 2, triB = itB * (itB + 1) / 2;

    const int t = threadIdx.x;
    const int lane = t & 63, w = t >> 6;        // 8 waves
    const int l16 = lane & 15, lg = lane >> 4;
    const int h0 = 2 * w;
    const size_t bh0 = (size_t)b * H_;
    _Float16* Eb = Ebuf + (size_t)b * 2080 * 4096;

    const half4v wpre_f = cvt4(*(const f32x4*)(Wpre + l16 * 16 + 4 * lg));

    half4v qf[2][2][4];
    #pragma unroll
    for (int s = 0; s < 2; ++s) {
        const int i0s = s ? i0B : i0A;
        #pragma unroll
        for (int e = 0; e < 2; ++e) {
            const float* qrow = q + ((bh0 + h0 + e) * N_ + i0s + l16) * D_;
            #pragma unroll
            for (int kk = 0; kk < 4; ++kk) {
                f32x4 qv = *(const f32x4*)(qrow + kk * 16 + 4 * lg);
                half4v hv;
                #pragma unroll
                for (int x = 0; x < 4; ++x) hv[x] = (_Float16)(qv[x] * 0.125f);
                qf[s][e][kk] = hv;
            }
        }
    }

    float lp[4][4];
    #pragma unroll
    for (int ss = 0; ss < 4; ++ss)
        #pragma unroll
        for (int r = 0; r < 4; ++r) lp[ss][r] = 0.f;

    int pbuf = 0;
    for (int sb = phase; 2 * sb <= itB; sb += 4) {
        #pragma unroll
        for (int u = 0; u < 2; ++u) {
            const int jt = 2 * sb + u;
            if (jt > itB) break;
            const int j0 = jt * 16;
            const bool actA = (jt <= itA);
            half4v kf[2][4];
            #pragma unroll
            for (int e = 0; e < 2; ++e) {
                const float* krow = k + ((bh0 + h0 + e) * N_ + j0 + l16) * D_ + 4 * lg;
                #pragma unroll
                for (int kk = 0; kk < 4; ++kk) kf[e][kk] = cvt4(*(const f32x4*)(krow + kk * 16));
            }
            #pragma unroll
            for (int s = 0; s < 2; ++s) {
                if (s == 0 && !actA) continue;
                #pragma unroll
                for (int e = 0; e < 2; ++e) {
                    f32x4 acc = {0.f, 0.f, 0.f, 0.f};
                    #pragma unroll
                    for (int kk = 0; kk < 4; ++kk)
                        acc = __builtin_amdgcn_mfma_f32_16x16x16f16(qf[s][e][kk], kf[e][kk], acc, 0, 0, 0);
                    #pragma unroll
                    for (int r = 0; r < 4; ++r)
                        Ss[pbuf][(s * 16 + 4 * lg + r) * SS_R + l16 * 20 + h0 + e] = (_Float16)acc[r];
                }
            }
            __syncthreads();
            #pragma unroll
            for (int ss = 0; ss < 4; ++ss) {
                const int strip = ss >> 1;
                if (strip == 0 && !actA) continue;
                const int sii = (ss & 1) * 8 + w;
                const int its = strip ? itB : itA;
                const int tri = strip ? triB : triA;
                half4v sfrag = *(const half4v*)&Ss[pbuf][(strip * 16 + sii) * SS_R + l16 * 20 + 4 * lg];
                f32x4 z = {0.f, 0.f, 0.f, 0.f};
                f32x4 m1 = __builtin_amdgcn_mfma_f32_16x16x16f16(wpre_f, sfrag, z, 0, 0, 0);
                const bool ok = (jt < its) || (l16 <= sii);
                half4v ev;
                #pragma unroll
                for (int r = 0; r < 4; ++r) {
                    const float e_ = ok ? __expf(m1[r]) : 0.f;
                    lp[ss][r] += e_;
                    ev[r] = (_Float16)e_;
                }
                *(half4v*)(Eb + (size_t)(tri + jt) * 4096 + (sii * 16 + l16) * 16 + 4 * lg) = ev;
            }
            pbuf ^= 1;
        }
    }

    #pragma unroll
    for (int ss = 0; ss < 4; ++ss) {
        const int strip = ss >> 1;
        const int sii = (ss & 1) * 8 + w;
        const int i0s = strip ? i0B : i0A;
        #pragma unroll
        for (int r = 0; r < 4; ++r) {
            float val = lp[ss][r];
            val += __shfl_xor(val, 1, 64);
            val += __shfl_xor(val, 2, 64);
            val += __shfl_xor(val, 4, 64);
            val += __shfl_xor(val, 8, 64);
            if (l16 == 0)
                atomicAdd(&lbuf[(bh0 + 4 * lg + r) * N_ + i0s + sii], val);
        }
    }
}

// ---------------- sweep 2: out = Wpost·(E/l)·V — KVBLK=64 (4 j-tiles / phase) ----------------
__global__ __launch_bounds__(512, 2)
void attend_sweep2(const _Float16* __restrict__ Ebuf, const _Float16* __restrict__ VT,
                   const float* __restrict__ Wpost, const float* __restrict__ lbuf,
                   float* __restrict__ out) {
    __shared__ _Float16 A2s[4][16 * A2_R];   // 41,984 B: 4 j-subtiles

    const int x = blockIdx.x;
    const int it = 63 - (x >> 3);             // descending: big tiles first
    const int sub = x & 7;
    const int b = sub >> 1, dh = sub & 1;
    const int i0 = it * 16;

    const int t = threadIdx.x;
    const int lane = t & 63, w = t >> 6;      // 8 waves
    const int l16 = lane & 15, lg = lane >> 4;
    const int h0 = 2 * w;
    const size_t bh0 = (size_t)b * H_;

    const half4v wpost_f = cvt4(*(const f32x4*)(Wpost + l16 * 16 + 4 * lg));

    // 1/l for softmax head 4lg+r at rows i0+sii (sii = ss*8+w)
    float lrecip[2][4];
    #pragma unroll
    for (int ss = 0; ss < 2; ++ss) {
        const int sii = ss * 8 + w;
        #pragma unroll
        for (int r = 0; r < 4; ++r)
            lrecip[ss][r] = 1.0f / lbuf[(bh0 + 4 * lg + r) * N_ + i0 + sii];
    }

    const _Float16* Eb = Ebuf + ((size_t)b * 2080 + (size_t)it * (it + 1) / 2) * 4096;

    f32x4 oacc[2][2];
    #pragma unroll
    for (int e = 0; e < 2; ++e)
        #pragma unroll
        for (int ds = 0; ds < 2; ++ds)
            oacc[e][ds] = (f32x4){0.f, 0.f, 0.f, 0.f};

    const int nph = (it + 4) >> 2;            // ceil((it+1)/4)
    for (int jb = 0; jb < nph; ++jb) {
        // VT fragments for all 4 subtiles FIRST — stay in flight across mix2 + barrier
        half4v vf[4][2][2];
        #pragma unroll
        for (int u = 0; u < 4; ++u) {
            const int jtc = min(jb * 4 + u, it);   // clamp: avoid OOB/NaN garbage
            #pragma unroll
            for (int e = 0; e < 2; ++e)
                #pragma unroll
                for (int ds = 0; ds < 2; ++ds)
                    vf[u][e][ds] = *(const half4v*)(VT + ((bh0 + h0 + e) * D_ + dh * 32 + ds * 16 + l16) * (size_t)N_ + jtc * 16 + 4 * lg);
        }
        // E load -> scale -> mix2 -> A2s (zeros for tail subtiles)
        #pragma unroll
        for (int u = 0; u < 4; ++u) {
            const int jt = jb * 4 + u;
            const bool valid = (jt <= it);
            #pragma unroll
            for (int ss = 0; ss < 2; ++ss) {
                const int sii = ss * 8 + w;
                half4v ef = valid
                    ? *(const half4v*)(Eb + (size_t)jt * 4096 + (sii * 16 + l16) * 16 + 4 * lg)
                    : (half4v){(_Float16)0.f, (_Float16)0.f, (_Float16)0.f, (_Float16)0.f};
                half4v pf;
                #pragma unroll
                for (int r = 0; r < 4; ++r)
                    pf[r] = (_Float16)((float)ef[r] * lrecip[ss][r]);
                f32x4 z = {0.f, 0.f, 0.f, 0.f};
                f32x4 m2 = __builtin_amdgcn_mfma_f32_16x16x16f16(wpost_f, pf, z, 0, 0, 0);
                #pragma unroll
                for (int r = 0; r < 4; ++r)
                    A2s[u][(4 * lg + r) * A2_R + sii * 20 + l16] = (_Float16)m2[r];
            }
        }
        __syncthreads();
        // PV: 16 MFMAs per phase
        #pragma unroll
        for (int u = 0; u < 4; ++u) {
            #pragma unroll
            for (int e = 0; e < 2; ++e) {
                const int g = h0 + e;
                half4v bfrag = *(const half4v*)&A2s[u][g * A2_R + l16 * 20 + 4 * lg];
                #pragma unroll
                for (int ds = 0; ds < 2; ++ds)
                    oacc[e][ds] = __builtin_amdgcn_mfma_f32_16x16x16f16(vf[u][e][ds], bfrag, oacc[e][ds], 0, 0, 0);
            }
        }
        __syncthreads();   // protect A2s before next phase overwrites
    }

    // plain stores — this WG exclusively owns (b, it-rows, all g, this d-half)
    #pragma unroll
    for (int e = 0; e < 2; ++e) {
        float* orow = out + ((bh0 + h0 + e) * N_ + i0 + l16) * D_;
        #pragma unroll
        for (int ds = 0; ds < 2; ++ds)
            *(f32x4*)&orow[dh * 32 + ds * 16 + 4 * lg] = oacc[e][ds];
    }
}

// ---------------- fallback: fused mirror-pair kernel (ws-free, verified R6) ----------------
__global__ __launch_bounds__(512, 2)
void attend_fused(const float* __restrict__ q, const float* __restrict__ k,
                  const float* __restrict__ v, const float* __restrict__ Wpre,
                  const float* __restrict__ Wpost, float* __restrict__ out) {
    __shared__ _Float16 Ss[32 * SS_R];
    __shared__ _Float16 A2s[16 * 648];

    const int t = threadIdx.x;
    const int b = blockIdx.x >> 5;
    const int m = blockIdx.x & 31;
    const int itA = m, itB = 63 - m;
    const int i0A = m * 16, i0B = (63 - m) * 16;

    const int lane = t & 63, w = t >> 6;
    const int l16 = lane & 15, lg = lane >> 4;
    const int h0 = 2 * w;
    const size_t bh0 = (size_t)b * H_;

    const half4v wpre_f  = cvt4(*(const f32x4*)(Wpre  + l16 * 16 + 4 * lg));
    const half4v wpost_f = cvt4(*(const f32x4*)(Wpost + l16 * 16 + 4 * lg));

    half4v qf[2][2][4];
    #pragma unroll
    for (int s = 0; s < 2; ++s) {
        const int i0s = s ? i0B : i0A;
        #pragma unroll
        for (int e = 0; e < 2; ++e) {
            const float* qrow = q + ((bh0 + h0 + e) * N_ + i0s + l16) * D_;
            #pragma unroll
            for (int kk = 0; kk < 4; ++kk) {
                f32x4 qv = *(const f32x4*)(qrow + kk * 16 + 4 * lg);
                half4v hv;
                #pragma unroll
                for (int x = 0; x < 4; ++x) hv[x] = (_Float16)(qv[x] * 0.125f);
                qf[s][e][kk] = hv;
            }
        }
    }

    float lp[4][4];
    #pragma unroll
    for (int ss = 0; ss < 4; ++ss)
        #pragma unroll
        for (int r = 0; r < 4; ++r) lp[ss][r] = 0.f;

    for (int jt = 0; jt <= itB; ++jt) {
        const int j0 = jt * 16;
        const bool actA = (jt <= itA);
        half4v kf[2][4];
        #pragma unroll
        for (int e = 0; e < 2; ++e) {
            const float* krow = k + ((bh0 + h0 + e) * N_ + j0 + l16) * D_ + 4 * lg;
            #pragma unroll
            for (int kk = 0; kk < 4; ++kk) kf[e][kk] = cvt4(*(const f32x4*)(krow + kk * 16));
        }
        #pragma unroll
        for (int s = 0; s < 2; ++s) {
            if (s == 0 && !actA) continue;
            #pragma unroll
            for (int e = 0; e < 2; ++e) {
                f32x4 acc = {0.f, 0.f, 0.f, 0.f};
                #pragma unroll
                for (int kk = 0; kk < 4; ++kk)
                    acc = __builtin_amdgcn_mfma_f32_16x16x16f16(qf[s][e][kk], kf[e][kk], acc, 0, 0, 0);
                #pragma unroll
                for (int r = 0; r < 4; ++r)
                    Ss[(s * 16 + 4 * lg + r) * SS_R + l16 * 20 + h0 + e] = (_Float16)acc[r];
            }
        }
        __syncthreads();
        #pragma unroll
        for (int ss = 0; ss < 4; ++ss) {
            const int strip = ss >> 1;
            if (strip == 0 && !actA) continue;
            const int sii = (ss & 1) * 8 + w;
            const int its = strip ? itB : itA;
            half4v sfrag = *(const half4v*)&Ss[(strip * 16 + sii) * SS_R + l16 * 20 + 4 * lg];
            f32x4 z = {0.f, 0.f, 0.f, 0.f};
            f32x4 m1 = __builtin_amdgcn_mfma_f32_16x16x16f16(wpre_f, sfrag, z, 0, 0, 0);
            if ((jt < its) || (l16 <= sii)) {
                #pragma unroll
                for (int r = 0; r < 4; ++r) lp[ss][r] += __expf(m1[r]);
            }
        }
        __syncthreads();
    }

    float lrec[4][4];
    #pragma unroll
    for (int ss = 0; ss < 4; ++ss)
        #pragma unroll
        for (int r = 0; r < 4; ++r) {
            float val = lp[ss][r];
            val += __shfl_xor(val, 1, 64);
            val += __shfl_xor(val, 2, 64);
            val += __shfl_xor(val, 4, 64);
            val += __shfl_xor(val, 8, 64);
            lrec[ss][r] = 1.0f / val;
        }

    f32x4 oacc[2][2][4];
    #pragma unroll
    for (int s = 0; s < 2; ++s)
        #pragma unroll
        for (int e = 0; e < 2; ++e)
            #pragma unroll
            for (int ds = 0; ds < 4; ++ds)
                oacc[s][e][ds] = (f32x4){0.f, 0.f, 0.f, 0.f};

    for (int jt = 0; jt <= itB; ++jt) {
        const int j0 = jt * 16;
        const bool actA = (jt <= itA);
        half4v kf[2][4];
        #pragma unroll
        for (int e = 0; e < 2; ++e) {
            const float* krow = k + ((bh0 + h0 + e) * N_ + j0 + l16) * D_ + 4 * lg;
            #pragma unroll
            for (int kk = 0; kk < 4; ++kk) kf[e][kk] = cvt4(*(const f32x4*)(krow + kk * 16));
        }
        half4v vf[2][4];
        #pragma unroll
        for (int e = 0; e < 2; ++e)
            #pragma unroll
            for (int ds = 0; ds < 4; ++ds) {
                f32x4 vv;
                #pragma unroll
                for (int xx = 0; xx < 4; ++xx)
                    vv[xx] = v[((bh0 + h0 + e) * N_ + j0 + 4 * lg + xx) * D_ + ds * 16 + l16];
                vf[e][ds] = cvt4(vv);
            }
        #pragma unroll
        for (int s = 0; s < 2; ++s) {
            if (s == 0 && !actA) continue;
            #pragma unroll
            for (int e = 0; e < 2; ++e) {
                f32x4 acc = {0.f, 0.f, 0.f, 0.f};
                #pragma unroll
                for (int kk = 0; kk < 4; ++kk)
                    acc = __builtin_amdgcn_mfma_f32_16x16x16f16(qf[s][e][kk], kf[e][kk], acc, 0, 0, 0);
                #pragma unroll
                for (int r = 0; r < 4; ++r)
                    Ss[(s * 16 + 4 * lg + r) * SS_R + l16 * 20 + h0 + e] = (_Float16)acc[r];
            }
        }
        __syncthreads();
        #pragma unroll
        for (int ss = 0; ss < 4; ++ss) {
            const int strip = ss >> 1;
            if (strip == 0 && !actA) continue;
            const int sii = (ss & 1) * 8 + w;
            const int its = strip ? itB : itA;
            half4v sfrag = *(const half4v*)&Ss[(strip * 16 + sii) * SS_R + l16 * 20 + 4 * lg];
            f32x4 z = {0.f, 0.f, 0.f, 0.f};
            f32x4 m1 = __builtin_amdgcn_mfma_f32_16x16x16f16(wpre_f, sfrag, z, 0, 0, 0);
            const bool ok = (jt < its) || (l16 <= sii);
            half4v pfrag;
            #pragma unroll
            for (int r = 0; r < 4; ++r)
                pfrag[r] = (_Float16)(ok ? __expf(m1[r]) * lrec[ss][r] : 0.f);
            f32x4 m2 = __builtin_amdgcn_mfma_f32_16x16x16f16(wpost_f, pfrag, z, 0, 0, 0);
            #pragma unroll
            for (int r = 0; r < 4; ++r)
                A2s[(4 * lg + r) * 648 + (strip * 16 + sii) * 20 + l16] = (_Float16)m2[r];
        }
        __syncthreads();
        #pragma unroll
        for (int s = 0; s < 2; ++s) {
            if (s == 0 && !actA) continue;
            #pragma unroll
            for (int e = 0; e < 2; ++e) {
                half4v bfrag = *(const half4v*)&A2s[(h0 + e) * 648 + (s * 16 + l16) * 20 + 4 * lg];
                #pragma unroll
                for (int ds = 0; ds < 4; ++ds)
                    oacc[s][e][ds] = __builtin_amdgcn_mfma_f32_16x16x16f16(vf[e][ds], bfrag, oacc[s][e][ds], 0, 0, 0);
            }
        }
    }

    #pragma unroll
    for (int s = 0; s < 2; ++s) {
        const int i0s = s ? i0B : i0A;
        #pragma unroll
        for (int e = 0; e < 2; ++e) {
            float* orow = out + ((bh0 + h0 + e) * N_ + i0s + l16) * D_;
            #pragma unroll
            for (int ds = 0; ds < 4; ++ds)
                *(f32x4*)&orow[ds * 16 + 4 * lg] = oacc[s][e][ds];
        }
    }
}

extern "C" void kernel_launch(void* const* d_in, const int* in_sizes, int n_in,
                              void* d_out, int out_size, void* d_ws, size_t ws_size,
                              hipStream_t stream) {
    const float* q     = (const float*)d_in[0];
    const float* k     = (const float*)d_in[1];
    const float* v     = (const float*)d_in[2];
    const float* Wpre  = (const float*)d_in[3];
    const float* Wpost = (const float*)d_in[4];
    float* out = (float*)d_out;
    _Float16* VT   = (_Float16*)((char*)d_ws + VT_OFF);
    float*    lbuf = (float*)((char*)d_ws + LB_OFF);
    _Float16* Ebuf = (_Float16*)((char*)d_ws + E_OFF);

    if (ws_size >= WS_NEED) {
        prep_vt<<<dim3(B_ * H_ * (N_ / 64)), dim3(256), 0, stream>>>(v, VT);
        hipMemsetAsync((char*)d_ws + LB_OFF, 0, LB_SZ, stream);
        attend_sweep1<<<dim3(512), dim3(512), 0, stream>>>(q, k, Wpre, lbuf, Ebuf);
        attend_sweep2<<<dim3(512), dim3(512), 0, stream>>>(Ebuf, VT, Wpost, lbuf, out);
    } else {
        attend_fused<<<dim3(B_ * 32), dim3(512), 0, stream>>>(q, k, v, Wpre, Wpost, out);
    }
}

// Round 11
// 160.745 us; speedup vs baseline: 1.4305x; 1.3052x over previous
//
#include <hip/hip_runtime.h>
#include <stdint.h>

#define B_  4
#define H_  16
#define N_  1024
#define D_  64
#define SS_R 328   // halfs per i-row of Ss: [i in 0..32)][j*20 + h], +8 pad
#define A2_R 328   // halfs per g-row of A2s: [g][i*20 + j], +8 pad

typedef _Float16 half4v __attribute__((ext_vector_type(4)));
typedef _Float16 half8v __attribute__((ext_vector_type(8)));
typedef float    f32x4  __attribute__((ext_vector_type(4)));

// workspace layout (bytes)
#define VT_OFF   0
#define VT_SZ    (B_ * H_ * D_ * N_ * 2)             // 8 MB
#define LB_OFF   (VT_OFF + VT_SZ)
#define LB_SZ    (B_ * H_ * N_ * 4)                  // 256 KB
#define E_OFF    (LB_OFF + LB_SZ)
#define E_SZ     ((size_t)B_ * 2080 * 4096 * 2)      // 65 MB causal-packed E
#define WS_NEED  ((size_t)E_OFF + E_SZ)              // 73.25 MB (< proven 80.25)

__device__ __forceinline__ half4v cvt4(f32x4 v) {
    half4v h;
    h[0] = (_Float16)v[0]; h[1] = (_Float16)v[1];
    h[2] = (_Float16)v[2]; h[3] = (_Float16)v[3];
    return h;
}

// decode blockIdx (0..511) -> slot grouped per XCD (consecutive slots same XCD)
__device__ __forceinline__ int xcd_slot(int x) { return (x >> 3) + (x & 7) * 64; }

// ---------------- prep: V transpose to f16 VT[b,h,d,j] ----------------
__global__ __launch_bounds__(256)
void prep_vt(const float* __restrict__ v, _Float16* __restrict__ VT) {
    __shared__ float T[64 * 67];
    const int t = threadIdx.x;
    const int bh = blockIdx.x >> 4, jb = blockIdx.x & 15, j0 = jb * 64;
    const float* src = v + ((size_t)bh * N_ + j0) * D_;
    #pragma unroll
    for (int m = 0; m < 4; ++m) {
        const int flat = m * 1024 + t * 4;
        const int j = flat >> 6, d0 = flat & 63;
        f32x4 val = *(const f32x4*)(src + flat);
        #pragma unroll
        for (int e = 0; e < 4; ++e) T[j * 67 + d0 + e] = val[e];
    }
    __syncthreads();
    const int d = t >> 2, jq = t & 3;
    half8v a, b2;
    #pragma unroll
    for (int jj = 0; jj < 8; ++jj) a[jj]  = (_Float16)T[(16 * jq + jj) * 67 + d];
    #pragma unroll
    for (int jj = 0; jj < 8; ++jj) b2[jj] = (_Float16)T[(16 * jq + 8 + jj) * 67 + d];
    _Float16* dst = VT + ((size_t)bh * D_ + d) * N_ + j0 + jq * 16;
    *(half8v*)dst = a;
    *(half8v*)(dst + 8) = b2;
}

// ---------------- sweep 1: l (atomic) + E cache (f16, causal-packed) ----------------
// E tile layout (halfs, 4096/tile): (i&7)*512 + j*32 + (h>>2)*8 + (i>>3)*4 + (h&3)
// -> sweep2 lane (j=l16, hq=lg) reads ONE half8v covering both i-parities.
__global__ __launch_bounds__(512, 2)
void attend_sweep1(const float* __restrict__ q, const float* __restrict__ k,
                   const float* __restrict__ Wpre, float* __restrict__ lbuf,
                   _Float16* __restrict__ Ebuf) {
    __shared__ _Float16 Ss[2][32 * SS_R];   // 41,984 B

    const int slot = xcd_slot(blockIdx.x);
    const int b = slot >> 7;
    const int r7 = slot & 127;
    const int m = r7 >> 2, phase = r7 & 3;
    const int itA = m, itB = 63 - m;
    const int i0A = m * 16, i0B = itB * 16;
    const int triA = itA * (itA + 1) / 2, triB = itB * (itB + 1) / 2;

    const int t = threadIdx.x;
    const int lane = t & 63, w = t >> 6;        // 8 waves
    const int l16 = lane & 15, lg = lane >> 4;
    const int h0 = 2 * w;
    const size_t bh0 = (size_t)b * H_;
    _Float16* Eb = Ebuf + (size_t)b * 2080 * 4096;

    const half4v wpre_f = cvt4(*(const f32x4*)(Wpre + l16 * 16 + 4 * lg));

    half4v qf[2][2][4];
    #pragma unroll
    for (int s = 0; s < 2; ++s) {
        const int i0s = s ? i0B : i0A;
        #pragma unroll
        for (int e = 0; e < 2; ++e) {
            const float* qrow = q + ((bh0 + h0 + e) * N_ + i0s + l16) * D_;
            #pragma unroll
            for (int kk = 0; kk < 4; ++kk) {
                f32x4 qv = *(const f32x4*)(qrow + kk * 16 + 4 * lg);
                half4v hv;
                #pragma unroll
                for (int x = 0; x < 4; ++x) hv[x] = (_Float16)(qv[x] * 0.125f);
                qf[s][e][kk] = hv;
            }
        }
    }

    float lp[4][4];
    #pragma unroll
    for (int ss = 0; ss < 4; ++ss)
        #pragma unroll
        for (int r = 0; r < 4; ++r) lp[ss][r] = 0.f;

    int pbuf = 0;
    for (int sb = phase; 2 * sb <= itB; sb += 4) {
        #pragma unroll
        for (int u = 0; u < 2; ++u) {
            const int jt = 2 * sb + u;
            if (jt > itB) break;
            const int j0 = jt * 16;
            const bool actA = (jt <= itA);
            half4v kf[2][4];
            #pragma unroll
            for (int e = 0; e < 2; ++e) {
                const float* krow = k + ((bh0 + h0 + e) * N_ + j0 + l16) * D_ + 4 * lg;
                #pragma unroll
                for (int kk = 0; kk < 4; ++kk) kf[e][kk] = cvt4(*(const f32x4*)(krow + kk * 16));
            }
            #pragma unroll
            for (int s = 0; s < 2; ++s) {
                if (s == 0 && !actA) continue;
                #pragma unroll
                for (int e = 0; e < 2; ++e) {
                    f32x4 acc = {0.f, 0.f, 0.f, 0.f};
                    #pragma unroll
                    for (int kk = 0; kk < 4; ++kk)
                        acc = __builtin_amdgcn_mfma_f32_16x16x16f16(qf[s][e][kk], kf[e][kk], acc, 0, 0, 0);
                    #pragma unroll
                    for (int r = 0; r < 4; ++r)
                        Ss[pbuf][(s * 16 + 4 * lg + r) * SS_R + l16 * 20 + h0 + e] = (_Float16)acc[r];
                }
            }
            __syncthreads();
            #pragma unroll
            for (int ss = 0; ss < 4; ++ss) {
                const int strip = ss >> 1;
                if (strip == 0 && !actA) continue;
                const int sii = (ss & 1) * 8 + w;
                const int its = strip ? itB : itA;
                const int tri = strip ? triB : triA;
                half4v sfrag = *(const half4v*)&Ss[pbuf][(strip * 16 + sii) * SS_R + l16 * 20 + 4 * lg];
                f32x4 z = {0.f, 0.f, 0.f, 0.f};
                f32x4 m1 = __builtin_amdgcn_mfma_f32_16x16x16f16(wpre_f, sfrag, z, 0, 0, 0);
                const bool ok = (jt < its) || (l16 <= sii);
                half4v ev;
                #pragma unroll
                for (int r = 0; r < 4; ++r) {
                    const float e_ = ok ? __expf(m1[r]) : 0.f;
                    lp[ss][r] += e_;
                    ev[r] = (_Float16)e_;
                }
                // new permuted tile layout: w*512 + j*32 + hq*8 + ipar*4
                *(half4v*)(Eb + (size_t)(tri + jt) * 4096 + w * 512 + l16 * 32 + lg * 8 + (ss & 1) * 4) = ev;
            }
            pbuf ^= 1;
        }
    }

    #pragma unroll
    for (int ss = 0; ss < 4; ++ss) {
        const int strip = ss >> 1;
        const int sii = (ss & 1) * 8 + w;
        const int i0s = strip ? i0B : i0A;
        #pragma unroll
        for (int r = 0; r < 4; ++r) {
            float val = lp[ss][r];
            val += __shfl_xor(val, 1, 64);
            val += __shfl_xor(val, 2, 64);
            val += __shfl_xor(val, 4, 64);
            val += __shfl_xor(val, 8, 64);
            if (l16 == 0)
                atomicAdd(&lbuf[(bh0 + 4 * lg + r) * N_ + i0s + sii], val);
        }
    }
}

// ---------------- sweep 2: out = Wpost·(E/l)·V — R8 pipeline, 4 blocks/CU ----------------
// grid 1024: r=x>>4 balanced pairing, (b, d-quarter)=x&15. 16B E loads, E prefetch.
__global__ __launch_bounds__(512, 8)
void attend_sweep2(const _Float16* __restrict__ Ebuf, const _Float16* __restrict__ VT,
                   const float* __restrict__ Wpost, const float* __restrict__ lbuf,
                   float* __restrict__ out) {
    __shared__ _Float16 A2s[2][16 * A2_R];   // 20,992 B

    const int x = blockIdx.x;
    const int r_ = x >> 4;
    const int it = (r_ < 32) ? (63 - r_) : (r_ - 32);   // quadruple sums constant
    const int sub = x & 15;
    const int b = sub >> 2, dq = sub & 3;
    const int i0 = it * 16;

    const int t = threadIdx.x;
    const int lane = t & 63, w = t >> 6;      // 8 waves
    const int l16 = lane & 15, lg = lane >> 4;
    const int h0 = 2 * w;
    const size_t bh0 = (size_t)b * H_;

    const half4v wpost_f = cvt4(*(const f32x4*)(Wpost + l16 * 16 + 4 * lg));

    // 1/l for softmax head 4lg+r at rows i0+sii (sii = ss*8+w)
    float lrecip[2][4];
    #pragma unroll
    for (int ss = 0; ss < 2; ++ss) {
        const int sii = ss * 8 + w;
        #pragma unroll
        for (int r = 0; r < 4; ++r)
            lrecip[ss][r] = 1.0f / lbuf[(bh0 + 4 * lg + r) * N_ + i0 + sii];
    }

    const _Float16* Eb = Ebuf + ((size_t)b * 2080 + (size_t)it * (it + 1) / 2) * 4096
                       + w * 512 + l16 * 32 + lg * 8;

    f32x4 oacc[2];
    #pragma unroll
    for (int e = 0; e < 2; ++e) oacc[e] = (f32x4){0.f, 0.f, 0.f, 0.f};

    int pb = 0;
    // prologue: E(0) — one 16B load covers both sii fragments
    half8v ecur = *(const half8v*)(Eb);

    for (int jt = 0; jt <= it; ++jt) {
        // VT fragments for this jt (in flight under mix2 + barrier)
        half4v vf[2];
        #pragma unroll
        for (int e = 0; e < 2; ++e)
            vf[e] = *(const half4v*)(VT + ((bh0 + h0 + e) * D_ + dq * 16 + l16) * (size_t)N_ + jt * 16 + 4 * lg);
        // mix2 from prefetched E
        #pragma unroll
        for (int ss = 0; ss < 2; ++ss) {
            const int sii = ss * 8 + w;
            half4v pf;
            #pragma unroll
            for (int r = 0; r < 4; ++r)
                pf[r] = (_Float16)((float)ecur[ss * 4 + r] * lrecip[ss][r]);
            f32x4 z = {0.f, 0.f, 0.f, 0.f};
            f32x4 m2 = __builtin_amdgcn_mfma_f32_16x16x16f16(wpost_f, pf, z, 0, 0, 0);
            #pragma unroll
            for (int r = 0; r < 4; ++r)
                A2s[pb][(4 * lg + r) * A2_R + sii * 20 + l16] = (_Float16)m2[r];
        }
        // prefetch E(jt+1) — stays in flight across the barrier
        half8v enext = ecur;
        if (jt < it) enext = *(const half8v*)(Eb + (size_t)(jt + 1) * 4096);
        __syncthreads();
        // PV
        #pragma unroll
        for (int e = 0; e < 2; ++e) {
            const int g = h0 + e;
            half4v bfrag = *(const half4v*)&A2s[pb][g * A2_R + l16 * 20 + 4 * lg];
            oacc[e] = __builtin_amdgcn_mfma_f32_16x16x16f16(vf[e], bfrag, oacc[e], 0, 0, 0);
        }
        ecur = enext;
        pb ^= 1;
    }

    // plain stores — WG exclusively owns (b, it-rows, all g, this d-quarter)
    #pragma unroll
    for (int e = 0; e < 2; ++e) {
        float* orow = out + ((bh0 + h0 + e) * N_ + i0 + l16) * D_;
        *(f32x4*)&orow[dq * 16 + 4 * lg] = oacc[e];
    }
}

// ---------------- fallback: fused mirror-pair kernel (ws-free, verified R6) ----------------
__global__ __launch_bounds__(512, 2)
void attend_fused(const float* __restrict__ q, const float* __restrict__ k,
                  const float* __restrict__ v, const float* __restrict__ Wpre,
                  const float* __restrict__ Wpost, float* __restrict__ out) {
    __shared__ _Float16 Ss[32 * SS_R];
    __shared__ _Float16 A2s[16 * 648];

    const int t = threadIdx.x;
    const int b = blockIdx.x >> 5;
    const int m = blockIdx.x & 31;
    const int itA = m, itB = 63 - m;
    const int i0A = m * 16, i0B = (63 - m) * 16;

    const int lane = t & 63, w = t >> 6;
    const int l16 = lane & 15, lg = lane >> 4;
    const int h0 = 2 * w;
    const size_t bh0 = (size_t)b * H_;

    const half4v wpre_f  = cvt4(*(const f32x4*)(Wpre  + l16 * 16 + 4 * lg));
    const half4v wpost_f = cvt4(*(const f32x4*)(Wpost + l16 * 16 + 4 * lg));

    half4v qf[2][2][4];
    #pragma unroll
    for (int s = 0; s < 2; ++s) {
        const int i0s = s ? i0B : i0A;
        #pragma unroll
        for (int e = 0; e < 2; ++e) {
            const float* qrow = q + ((bh0 + h0 + e) * N_ + i0s + l16) * D_;
            #pragma unroll
            for (int kk = 0; kk < 4; ++kk) {
                f32x4 qv = *(const f32x4*)(qrow + kk * 16 + 4 * lg);
                half4v hv;
                #pragma unroll
                for (int x = 0; x < 4; ++x) hv[x] = (_Float16)(qv[x] * 0.125f);
                qf[s][e][kk] = hv;
            }
        }
    }

    float lp[4][4];
    #pragma unroll
    for (int ss = 0; ss < 4; ++ss)
        #pragma unroll
        for (int r = 0; r < 4; ++r) lp[ss][r] = 0.f;

    for (int jt = 0; jt <= itB; ++jt) {
        const int j0 = jt * 16;
        const bool actA = (jt <= itA);
        half4v kf[2][4];
        #pragma unroll
        for (int e = 0; e < 2; ++e) {
            const float* krow = k + ((bh0 + h0 + e) * N_ + j0 + l16) * D_ + 4 * lg;
            #pragma unroll
            for (int kk = 0; kk < 4; ++kk) kf[e][kk] = cvt4(*(const f32x4*)(krow + kk * 16));
        }
        #pragma unroll
        for (int s = 0; s < 2; ++s) {
            if (s == 0 && !actA) continue;
            #pragma unroll
            for (int e = 0; e < 2; ++e) {
                f32x4 acc = {0.f, 0.f, 0.f, 0.f};
                #pragma unroll
                for (int kk = 0; kk < 4; ++kk)
                    acc = __builtin_amdgcn_mfma_f32_16x16x16f16(qf[s][e][kk], kf[e][kk], acc, 0, 0, 0);
                #pragma unroll
                for (int r = 0; r < 4; ++r)
                    Ss[(s * 16 + 4 * lg + r) * SS_R + l16 * 20 + h0 + e] = (_Float16)acc[r];
            }
        }
        __syncthreads();
        #pragma unroll
        for (int ss = 0; ss < 4; ++ss) {
            const int strip = ss >> 1;
            if (strip == 0 && !actA) continue;
            const int sii = (ss & 1) * 8 + w;
            const int its = strip ? itB : itA;
            half4v sfrag = *(const half4v*)&Ss[(strip * 16 + sii) * SS_R + l16 * 20 + 4 * lg];
            f32x4 z = {0.f, 0.f, 0.f, 0.f};
            f32x4 m1 = __builtin_amdgcn_mfma_f32_16x16x16f16(wpre_f, sfrag, z, 0, 0, 0);
            if ((jt < its) || (l16 <= sii)) {
                #pragma unroll
                for (int r = 0; r < 4; ++r) lp[ss][r] += __expf(m1[r]);
            }
        }
        __syncthreads();
    }

    float lrec[4][4];
    #pragma unroll
    for (int ss = 0; ss < 4; ++ss)
        #pragma unroll
        for (int r = 0; r < 4; ++r) {
            float val = lp[ss][r];
            val += __shfl_xor(val, 1, 64);
            val += __shfl_xor(val, 2, 64);
            val += __shfl_xor(val, 4, 64);
            val += __shfl_xor(val, 8, 64);
            lrec[ss][r] = 1.0f / val;
        }

    f32x4 oacc[2][2][4];
    #pragma unroll
    for (int s = 0; s < 2; ++s)
        #pragma unroll
        for (int e = 0; e < 2; ++e)
            #pragma unroll
            for (int ds = 0; ds < 4; ++ds)
                oacc[s][e][ds] = (f32x4){0.f, 0.f, 0.f, 0.f};

    for (int jt = 0; jt <= itB; ++jt) {
        const int j0 = jt * 16;
        const bool actA = (jt <= itA);
        half4v kf[2][4];
        #pragma unroll
        for (int e = 0; e < 2; ++e) {
            const float* krow = k + ((bh0 + h0 + e) * N_ + j0 + l16) * D_ + 4 * lg;
            #pragma unroll
            for (int kk = 0; kk < 4; ++kk) kf[e][kk] = cvt4(*(const f32x4*)(krow + kk * 16));
        }
        half4v vf[2][4];
        #pragma unroll
        for (int e = 0; e < 2; ++e)
            #pragma unroll
            for (int ds = 0; ds < 4; ++ds) {
                f32x4 vv;
                #pragma unroll
                for (int xx = 0; xx < 4; ++xx)
                    vv[xx] = v[((bh0 + h0 + e) * N_ + j0 + 4 * lg + xx) * D_ + ds * 16 + l16];
                vf[e][ds] = cvt4(vv);
            }
        #pragma unroll
        for (int s = 0; s < 2; ++s) {
            if (s == 0 && !actA) continue;
            #pragma unroll
            for (int e = 0; e < 2; ++e) {
                f32x4 acc = {0.f, 0.f, 0.f, 0.f};
                #pragma unroll
                for (int kk = 0; kk < 4; ++kk)
                    acc = __builtin_amdgcn_mfma_f32_16x16x16f16(qf[s][e][kk], kf[e][kk], acc, 0, 0, 0);
                #pragma unroll
                for (int r = 0; r < 4; ++r)
                    Ss[(s * 16 + 4 * lg + r) * SS_R + l16 * 20 + h0 + e] = (_Float16)acc[r];
            }
        }
        __syncthreads();
        #pragma unroll
        for (int ss = 0; ss < 4; ++ss) {
            const int strip = ss >> 1;
            if (strip == 0 && !actA) continue;
            const int sii = (ss & 1) * 8 + w;
            const int its = strip ? itB : itA;
            half4v sfrag = *(const half4v*)&Ss[(strip * 16 + sii) * SS_R + l16 * 20 + 4 * lg];
            f32x4 z = {0.f, 0.f, 0.f, 0.f};
            f32x4 m1 = __builtin_amdgcn_mfma_f32_16x16x16f16(wpre_f, sfrag, z, 0, 0, 0);
            const bool ok = (jt < its) || (l16 <= sii);
            half4v pfrag;
            #pragma unroll
            for (int r = 0; r < 4; ++r)
                pfrag[r] = (_Float16)(ok ? __expf(m1[r]) * lrec[ss][r] : 0.f);
            f32x4 m2 = __builtin_amdgcn_mfma_f32_16x16x16f16(wpost_f, pfrag, z, 0, 0, 0);
            #pragma unroll
            for (int r = 0; r < 4; ++r)
                A2s[(4 * lg + r) * 648 + (strip * 16 + sii) * 20 + l16] = (_Float16)m2[r];
        }
        __syncthreads();
        #pragma unroll
        for (int s = 0; s < 2; ++s) {
            if (s == 0 && !actA) continue;
            #pragma unroll
            for (int e = 0; e < 2; ++e) {
                half4v bfrag = *(const half4v*)&A2s[(h0 + e) * 648 + (s * 16 + l16) * 20 + 4 * lg];
                #pragma unroll
                for (int ds = 0; ds < 4; ++ds)
                    oacc[s][e][ds] = __builtin_amdgcn_mfma_f32_16x16x16f16(vf[e][ds], bfrag, oacc[s][e][ds], 0, 0, 0);
            }
        }
    }

    #pragma unroll
    for (int s = 0; s < 2; ++s) {
        const int i0s = s ? i0B : i0A;
        #pragma unroll
        for (int e = 0; e < 2; ++e) {
            float* orow = out + ((bh0 + h0 + e) * N_ + i0s + l16) * D_;
            #pragma unroll
            for (int ds = 0; ds < 4; ++ds)
                *(f32x4*)&orow[ds * 16 + 4 * lg] = oacc[s][e][ds];
        }
    }
}

extern "C" void kernel_launch(void* const* d_in, const int* in_sizes, int n_in,
                              void* d_out, int out_size, void* d_ws, size_t ws_size,
                              hipStream_t stream) {
    const float* q     = (const float*)d_in[0];
    const float* k     = (const float*)d_in[1];
    const float* v     = (const float*)d_in[2];
    const float* Wpre  = (const float*)d_in[3];
    const float* Wpost = (const float*)d_in[4];
    float* out = (float*)d_out;
    _Float16* VT   = (_Float16*)((char*)d_ws + VT_OFF);
    float*    lbuf = (float*)((char*)d_ws + LB_OFF);
    _Float16* Ebuf = (_Float16*)((char*)d_ws + E_OFF);

    if (ws_size >= WS_NEED) {
        prep_vt<<<dim3(B_ * H_ * (N_ / 64)), dim3(256), 0, stream>>>(v, VT);
        hipMemsetAsync((char*)d_ws + LB_OFF, 0, LB_SZ, stream);
        attend_sweep1<<<dim3(512), dim3(512), 0, stream>>>(q, k, Wpre, lbuf, Ebuf);
        attend_sweep2<<<dim3(1024), dim3(512), 0, stream>>>(Ebuf, VT, Wpost, lbuf, out);
    } else {
        attend_fused<<<dim3(B_ * 32), dim3(512), 0, stream>>>(q, k, v, Wpre, Wpost, out);
    }
}